// Round 1
// baseline (783.033 us; speedup 1.0000x reference)
//
#include <hip/hip_runtime.h>

#define NTAG 128
#define SEQ 512
#define NBATCH 512
#define END_ID 1

// One block per batch. Thread j owns tag j. E = exp(trans[j][*]) lives in
// 128 VGPRs per thread (zero LDS traffic for the matrix). Per step:
//   m = block max(alpha); p[k] = exp(alpha[k]-m) via LDS;
//   q[j] = sum_k p[k]*E[j][k]  (32 x float4-broadcast + 4 FMA);
//   alpha[j] = x[t][j] + m + log(q[j]).
// Early exit at t == len (mask is monotonic: mask[b][t] = t < len).
__global__ __launch_bounds__(128) void crf_kernel(
    const float* __restrict__ x,      // [B,S,T]
    const int*   __restrict__ tags,   // [B,S]
    const float* __restrict__ mask,   // [B,S]
    const float* __restrict__ trans,  // [T,T]
    float* __restrict__ ws)           // [B]: fwd - gold
{
  const int b    = blockIdx.x;
  const int j    = threadIdx.x;
  const int lane = j & 63;
  const int wv   = j >> 6;

  __shared__ float p_lds[NTAG];
  __shared__ float red[8];

  const float* xb   = x    + (size_t)b * SEQ * NTAG;
  const float* mrow = mask + (size_t)b * SEQ;
  const int*   trow = tags + (size_t)b * SEQ;

  // ---- len = sum(mask row) (exact: mask is 0.0/1.0) ----
  float msum = 0.f;
  #pragma unroll
  for (int i = 0; i < SEQ / 128; ++i) msum += mrow[j + i * 128];
  #pragma unroll
  for (int off = 1; off < 64; off <<= 1) msum += __shfl_xor(msum, off);
  if (lane == 0) red[wv] = msum;
  __syncthreads();
  const int len = (int)(red[0] + red[1]);   // in [1, 510]
  __syncthreads();

  // ---- E = exp(trans row j) into registers (one-time, cache-hot) ----
  float e[NTAG];
  {
    const float4* tr4 = (const float4*)(trans + j * NTAG);
    #pragma unroll
    for (int k4 = 0; k4 < NTAG / 4; ++k4) {
      float4 v = tr4[k4];
      e[4 * k4 + 0] = __expf(v.x);
      e[4 * k4 + 1] = __expf(v.y);
      e[4 * k4 + 2] = __expf(v.z);
      e[4 * k4 + 3] = __expf(v.w);
    }
  }

  float a  = (j == 0) ? 0.f : -10000.f;   // START_ID = 0
  float xt = xb[j];                       // x[b][0][j]

  for (int t = 0; t < len; ++t) {
    // block max of alpha
    float wm = a;
    #pragma unroll
    for (int off = 1; off < 64; off <<= 1) wm = fmaxf(wm, __shfl_xor(wm, off));
    if (lane == 0) red[wv] = wm;
    __syncthreads();
    const float m = fmaxf(red[0], red[1]);

    p_lds[j] = __expf(a - m);   // p[j] in [0,1]; exp(-1e4) flushes to 0 (ok)
    __syncthreads();

    // prefetch next timestep's emission (t+1 <= len <= 510 < SEQ)
    float xn = xb[(size_t)(t + 1) * NTAG + j];

    const float4* p4 = (const float4*)p_lds;
    float q0 = 0.f, q1 = 0.f, q2 = 0.f, q3 = 0.f;
    #pragma unroll
    for (int k4 = 0; k4 < NTAG / 4; ++k4) {
      float4 pv = p4[k4];                 // LDS broadcast (no bank conflict)
      q0 = fmaf(pv.x, e[4 * k4 + 0], q0);
      q1 = fmaf(pv.y, e[4 * k4 + 1], q1);
      q2 = fmaf(pv.z, e[4 * k4 + 2], q2);
      q3 = fmaf(pv.w, e[4 * k4 + 3], q3);
    }
    // q >= min(E) since max-normalized p has a 1.0 entry -> log well-conditioned
    a  = xt + m + __logf((q0 + q1) + (q2 + q3));
    xt = xn;
  }

  // ---- fwd = logsumexp_j(alpha[j] + trans[END][j]) ----
  __syncthreads();
  float v = a + trans[END_ID * NTAG + j];
  float wm = v;
  #pragma unroll
  for (int off = 1; off < 64; off <<= 1) wm = fmaxf(wm, __shfl_xor(wm, off));
  if (lane == 0) red[wv] = wm;
  __syncthreads();
  const float m2 = fmaxf(red[0], red[1]);
  float s = __expf(v - m2);
  #pragma unroll
  for (int off = 1; off < 64; off <<= 1) s += __shfl_xor(s, off);
  if (lane == 0) red[4 + wv] = s;
  __syncthreads();
  const float fwd = m2 + __logf(red[4] + red[5]);

  // ---- gold score: sum_{i<len} x[b,i,tag[i+1]] + trans[tag[i+1],tag[i]] ----
  float g = 0.f;
  for (int i = j; i < len; i += 128) {
    int tn = trow[i + 1];
    int tp = trow[i];
    g += xb[(size_t)i * NTAG + tn] + trans[tn * NTAG + tp];
  }
  #pragma unroll
  for (int off = 1; off < 64; off <<= 1) g += __shfl_xor(g, off);
  __syncthreads();
  if (lane == 0) red[2 + wv] = g;
  __syncthreads();
  if (j == 0) {
    float gold = red[2] + red[3] + trans[END_ID * NTAG + trow[len]];
    ws[b] = fwd - gold;
  }
}

__global__ void reduce_kernel(const float* __restrict__ ws, float* __restrict__ out) {
  __shared__ float sm[8];
  const int tid = threadIdx.x;   // 512
  float v = ws[tid];
  #pragma unroll
  for (int off = 1; off < 64; off <<= 1) v += __shfl_xor(v, off);
  if ((tid & 63) == 0) sm[tid >> 6] = v;
  __syncthreads();
  if (tid == 0) {
    float s = 0.f;
    #pragma unroll
    for (int w = 0; w < 8; ++w) s += sm[w];
    out[0] = s * (1.0f / 512.0f);
  }
}

extern "C" void kernel_launch(void* const* d_in, const int* in_sizes, int n_in,
                              void* d_out, int out_size, void* d_ws, size_t ws_size,
                              hipStream_t stream) {
  const float* x     = (const float*)d_in[0];
  const int*   tags  = (const int*)d_in[1];
  const float* mask  = (const float*)d_in[2];
  const float* trans = (const float*)d_in[3];
  float*       ws    = (float*)d_ws;

  crf_kernel<<<NBATCH, 128, 0, stream>>>(x, tags, mask, trans, ws);
  reduce_kernel<<<1, 512, 0, stream>>>(ws, (float*)d_out);
}